// Round 1
// baseline (15370.564 us; speedup 1.0000x reference)
//
#include <hip/hip_runtime.h>

// LSTM: T=512, B=64, IN=512, H=1024, 4H=4096, LAYERS=4, OUT=1
// R5: self-timed point-to-point pipeline — no global barrier. FLAG[W] = count
// of completed local timesteps of WG W (posted after vmcnt-draining
// __syncthreads, same visibility chain as the verified R4 kernel). Each wave
// polls only its true dependencies with wave-specialized thresholds:
//   P0-reading waves (cross-layer): FLAG[l-1][*] >= t+1
//   P1-reading waves (own-layer h): FLAG[l][*]   >= t
//   ring backpressure (slot t&31 overwrite kills h(t-32)): FLAG[l+1][*] >= t-31
// DAG (l,t) -> {(l-1,t),(l,t-1),(l+1,t-32)} is acyclic => deadlock-free.
// A-prefetch depth 4 -> 8 (LLC-latency-bound loop), R double-buffered so the
// zero pass folds into the gate phase (2 intra-WG barriers/step).

typedef unsigned short u16;
typedef short bf16x8 __attribute__((ext_vector_type(8)));
typedef float f32x4 __attribute__((ext_vector_type(4)));
typedef float f32x16 __attribute__((ext_vector_type(16)));

__device__ __forceinline__ u16 f2bf(float f) {
  unsigned u = __float_as_uint(f);
  return (u16)((u + 0x7FFFu + ((u >> 16) & 1u)) >> 16);   // RNE
}
__device__ __forceinline__ float bf2f(u16 s) {
  return __uint_as_float(((unsigned)s) << 16);
}
__device__ __forceinline__ bf16x8 ld8(const u16* p) {
  uint4 v = *(const uint4*)p;
  return __builtin_bit_cast(bf16x8, v);
}
__device__ __forceinline__ float sigf(float x) {
  x = fminf(fmaxf(x, -30.f), 30.f);
  return 1.f / (1.f + __expf(-x));
}
__device__ __forceinline__ float tanhf_(float x) {
  x = fminf(fmaxf(x, -15.f), 15.f);
  float e = __expf(-2.f * x);
  return (1.f - e) / (1.f + e);
}

#define AT_LD(p) __hip_atomic_load((p), __ATOMIC_RELAXED, __HIP_MEMORY_SCOPE_AGENT)
#define AT_ST(p, v) __hip_atomic_store((p), (v), __ATOMIC_RELAXED, __HIP_MEMORY_SCOPE_AGENT)

// ---------------- repack: W -> WCAT[l][4096][2048] bf16 ----------------
// cols [0,Kx) = W_ih_l, [Kx,Kx+1024) = W_hh_l, rest 0. Kx = 512 (l=0) else 1024.
__global__ void repack_w(const float* __restrict__ wih0, const float* __restrict__ wihr,
                         const float* __restrict__ whh, u16* __restrict__ WCAT) {
  size_t i = (size_t)blockIdx.x * 256 + threadIdx.x;   // 33554432 total
  int l = (int)(i >> 23);
  int r = (int)(i >> 11) & 4095;
  int c = (int)i & 2047;
  int Kx = l ? 1024 : 512;
  float v = 0.f;
  if (c < Kx) v = l ? wihr[((size_t)(l - 1) * 4096 + r) * 1024 + c]
                    : wih0[(size_t)r * 512 + c];
  else if (c < Kx + 1024) v = whh[((size_t)l * 4096 + r) * 1024 + (c - Kx)];
  WCAT[i] = f2bf(v);
}

// ---------------- repack: x -> XP[t][kc(64)][b(64)][8] bf16 ----------------
__global__ void repack_x(const float* __restrict__ x, u16* __restrict__ XP) {
  int i = blockIdx.x * 256 + threadIdx.x;   // 2097152 total
  int t = i >> 12, r = i & 4095, kc = r >> 6, b = r & 63;
  const float* src = x + ((size_t)t * 64 + b) * 512 + kc * 8;
  float4 v0 = *(const float4*)src, v1 = *(const float4*)(src + 4);
  u16 o[8] = {f2bf(v0.x), f2bf(v0.y), f2bf(v0.z), f2bf(v0.w),
              f2bf(v1.x), f2bf(v1.y), f2bf(v1.z), f2bf(v1.w)};
  *(uint4*)(XP + ((size_t)(t * 64 + kc) * 64 + b) * 8) = *(uint4*)o;
}

__global__ void bias_add(const float* __restrict__ a, const float* __restrict__ b,
                         float* __restrict__ o) {
  int i = blockIdx.x * blockDim.x + threadIdx.x;   // 16384 total
  o[i] = a[i] + b[i];
}

// ---------------- pipelined recurrence ----------------
// WG w: layer = w>>6, owns units [16(w&63), +16) -> 64 gate-rows.
// 8 waves = (ks in 0..3, nh in 0..1): K-slice of NF frags (16k each), rows 32nh..+32.
// Each wave: 2 m-tiles (batch 0..31, 32..63) -> acc0/acc1, shared wf[] B-frags.
template <int NF, int FX>
__device__ __forceinline__ void run_pipe(
    int layer, int w64, const u16* __restrict__ WCAT, const u16* __restrict__ XP,
    u16* __restrict__ HR, u16* __restrict__ HOUT, const float* __restrict__ BIAS,
    int* __restrict__ FLAG, float* R) {
  const int tid = threadIdx.x;
  const int lane = tid & 63, wv = tid >> 6;
  const int ks = wv & 3, nh = wv >> 2;
  const int l31 = lane & 31, lhi = lane >> 5;
  const int W = layer * 64 + w64;

  // ---- W preload: NF frags = 4*NF VGPRs, persistent ----
  bf16x8 wf[NF];
  {
    const int lr = nh * 32 + l31;
    const int grow = (lr >> 4) * 1024 + 16 * w64 + (lr & 15);
    const u16* wrow = WCAT + ((size_t)layer * 4096 + grow) * 2048;
#pragma unroll
    for (int kk = 0; kk < NF; ++kk) {
      int f = ks * NF + kk;
      wf[kk] = ld8(wrow + f * 16 + lhi * 8);
    }
  }

  const int u = tid & 15, bp = tid >> 4;       // gating: (batch bp & bp+32, unit u)
  const int col = 16 * w64 + u;
  float c0 = 0.f, c1 = 0.f;
  const float bi = BIAS[layer * 4096 + col];
  const float bf_ = BIAS[layer * 4096 + 1024 + col];
  const float bg = BIAS[layer * 4096 + 2048 + col];
  const float bo = BIAS[layer * 4096 + 3072 + col];

  const int lane_base = (lhi * 64 + l31) * 8;  // mt0; mt1 adds +256 elems
  u16* HRL = HR + (size_t)layer * 2097152;                       // own ring (32 slots)
  const u16* M0B = (NF == 32) ? HR + (size_t)(layer - 1) * 2097152 : XP;
  const int lrD = nh * 32 + l31;               // C/D col -> local gate-row

  // ---- p2p sync setup: which inputs does THIS wave actually read? ----
  // wave covers frags [ks*NF, ks*NF+NF): f < FX  -> P0 (layer below / XP)
  //                                      f >= FX -> P1 (own-layer h(t-1))
  const bool needA = (layer > 0) && (ks * NF < FX);    // cross-layer P0
  const bool needB = (ks * NF + NF > FX);              // own-layer P1
  const bool needC = (layer < 3);                      // ring backpressure
  const int lm1 = (layer > 0) ? layer - 1 : layer;
  const int lp1 = (layer < 3) ? layer + 1 : layer;
  int* fA = FLAG + (lm1 * 64 + lane) * 64;
  int* fB = FLAG + (layer * 64 + lane) * 64;
  int* fC = FLAG + (lp1 * 64 + lane) * 64;
  const int NEVER = -0x40000000;

  // zero R buffer 0 (buffer 1 is zeroed in step 0's gate phase)
  *(f32x4*)&R[tid * 8] = f32x4{0.f, 0.f, 0.f, 0.f};
  *(f32x4*)&R[tid * 8 + 4] = f32x4{0.f, 0.f, 0.f, 0.f};
  __syncthreads();

  for (int t = 0; t < 512; ++t) {
    // ---- per-wave dependency poll (1-hop, no global barrier) ----
    {
      const int thA = needA ? t + 1 : NEVER;   // layer l-1 finished t
      const int thB = needB ? t : NEVER;       // own layer finished t-1
      const int thC = needC ? t - 31 : NEVER;  // layer l+1 finished t-32
      for (;;) {
        bool ok = (AT_LD(fA) >= thA) & (AT_LD(fB) >= thB) & (AT_LD(fC) >= thC);
        if (__ballot(ok) == ~0ull) break;
        __builtin_amdgcn_s_sleep(1);
      }
    }

    float* Rb = R + (t & 1) * 4096;
    const u16* P0 = M0B + ((NF == 32) ? (size_t)(t & 31) * 65536
                                      : (size_t)t * 32768) + lane_base;
    const u16* P1 = HRL + (size_t)((t - 1) & 31) * 65536 + lane_base - (size_t)FX * 1024;

    f32x16 acc0 = {}, acc1 = {};
    uint4 a0[8], a1[8];
#pragma unroll
    for (int p = 0; p < 8; ++p) {
      int f = ks * NF + p;
      const u16* ap = (f < FX ? P0 : P1) + (size_t)f * 1024;
      a0[p] = *(const uint4*)ap;
      a1[p] = *(const uint4*)(ap + 256);
    }
#pragma unroll
    for (int kk = 0; kk < NF; ++kk) {
      uint4 ca = a0[kk & 7], cb = a1[kk & 7];
      if (kk + 8 < NF) {
        int f = ks * NF + kk + 8;
        const u16* ap = (f < FX ? P0 : P1) + (size_t)f * 1024;
        a0[kk & 7] = *(const uint4*)ap;
        a1[kk & 7] = *(const uint4*)(ap + 256);
      }
      acc0 = __builtin_amdgcn_mfma_f32_32x32x16_bf16(
          __builtin_bit_cast(bf16x8, ca), wf[kk], acc0, 0, 0, 0);
      acc1 = __builtin_amdgcn_mfma_f32_32x32x16_bf16(
          __builtin_bit_cast(bf16x8, cb), wf[kk], acc1, 0, 0, 0);
    }
#pragma unroll
    for (int r = 0; r < 16; ++r) {
      int m = (r & 3) + 8 * (r >> 2) + 4 * lhi;    // 32x32 C/D row map (m101)
      atomicAdd(&Rb[m * 64 + lrD], acc0[r]);
      atomicAdd(&Rb[(32 + m) * 64 + lrD], acc1[r]);
    }
    __syncthreads();
    {
      float p0i = Rb[bp * 64 + u] + bi, p0f = Rb[bp * 64 + 16 + u] + bf_;
      float p0g = Rb[bp * 64 + 32 + u] + bg, p0o = Rb[bp * 64 + 48 + u] + bo;
      float p1i = Rb[(bp + 32) * 64 + u] + bi, p1f = Rb[(bp + 32) * 64 + 16 + u] + bf_;
      float p1g = Rb[(bp + 32) * 64 + 32 + u] + bg, p1o = Rb[(bp + 32) * 64 + 48 + u] + bo;
      c0 = sigf(p0f) * c0 + sigf(p0i) * tanhf_(p0g);
      float h0 = sigf(p0o) * tanhf_(c0);
      c1 = sigf(p1f) * c1 + sigf(p1i) * tanhf_(p1g);
      float h1 = sigf(p1o) * tanhf_(c1);
      u16 hb0 = f2bf(h0), hb1 = f2bf(h1);
      unsigned n0 = (unsigned)(u16)__shfl_down((int)(unsigned)hb0, 1, 64);
      unsigned n1 = (unsigned)(u16)__shfl_down((int)(unsigned)hb1, 1, 64);
      if ((u & 1) == 0) {
        unsigned pk0 = (unsigned)hb0 | (n0 << 16);
        unsigned pk1 = (unsigned)hb1 | (n1 << 16);
        u16* slot = HRL + (size_t)(t & 31) * 65536;
        size_t e0 = ((size_t)(col >> 3) * 64 + bp) * 8 + (col & 7);
        AT_ST((unsigned*)(slot + e0), pk0);
        AT_ST((unsigned*)(slot + e0 + 256), pk1);   // b+32
        if (layer == 3 && bp == 31)                 // batch 63 for the head
          *(unsigned*)(HOUT + (size_t)t * 1024 + col) = pk1;
      }
      // fold zero-pass of the other R buffer into the gate phase
      float* Rn = R + ((t + 1) & 1) * 4096;
      *(f32x4*)&Rn[tid * 8] = f32x4{0.f, 0.f, 0.f, 0.f};
      *(f32x4*)&Rn[tid * 8 + 4] = f32x4{0.f, 0.f, 0.f, 0.f};
    }
    __syncthreads();   // drains vmcnt(0): ring stores at coherence point
    if (tid == 0) AT_ST(&FLAG[W * 64], t + 1);   // 1-hop progress post
  }
}

__global__ __launch_bounds__(512, 2) void lstm_pipe(
    const u16* __restrict__ WCAT, const u16* __restrict__ XP,
    u16* __restrict__ HR, u16* __restrict__ HOUT,
    const float* __restrict__ BIAS, int* __restrict__ FLAG) {
  __shared__ float R[2 * 4096];
  const int w = blockIdx.x;
  const int layer = w >> 6, w64 = w & 63;
  if (layer == 0) run_pipe<24, 32>(0, w64, WCAT, XP, HR, HOUT, BIAS, FLAG, R);
  else            run_pipe<32, 64>(layer, w64, WCAT, XP, HR, HOUT, BIAS, FLAG, R);
}

// ---------------- head: out[t] = sigmoid(h3[t][63][:]) . fcw + fcb ----------------
__global__ void lstm_head(const u16* __restrict__ Hl, const float* __restrict__ fcw,
                          const float* __restrict__ fcb, float* __restrict__ out) {
  int t = blockIdx.x, tid = threadIdx.x;
  const u16* hrow = Hl + (size_t)t * 1024;
  float s = 0.f;
  for (int j = tid; j < 1024; j += 256)
    s += sigf(bf2f(hrow[j])) * fcw[j];
  for (int o = 32; o; o >>= 1) s += __shfl_down(s, o, 64);
  __shared__ float red[4];
  if ((tid & 63) == 0) red[tid >> 6] = s;
  __syncthreads();
  if (tid == 0) out[t] = red[0] + red[1] + red[2] + red[3] + fcb[0];
}

// ---------------- launch ----------------
extern "C" void kernel_launch(void* const* d_in, const int* in_sizes, int n_in,
                              void* d_out, int out_size, void* d_ws, size_t ws_size,
                              hipStream_t stream) {
  const float* x    = (const float*)d_in[0];
  const float* wih0 = (const float*)d_in[1];
  const float* wihr = (const float*)d_in[2];
  const float* whh  = (const float*)d_in[3];
  const float* bih  = (const float*)d_in[4];
  const float* bhh  = (const float*)d_in[5];
  const float* fcw  = (const float*)d_in[6];
  const float* fcb  = (const float*)d_in[7];
  float* out = (float*)d_out;

  char* ws = (char*)d_ws;
  size_t off = 0;
  auto alc = [&](size_t b) { void* p = ws + off; off = (off + b + 255) & ~(size_t)255; return p; };
  u16* WCAT  = (u16*)alc(33554432ull * 2);   // 64 MB
  u16* XP    = (u16*)alc(16777216ull * 2);   // 32 MB
  u16* HR    = (u16*)alc(8388608ull * 2);    // 16 MB (4 layers x 32 slots x 128 KB)
  u16* HOUT  = (u16*)alc(524288ull * 2);     // 1 MB
  float* BIAS = (float*)alc(16384 * 4);
  int* FLAG  = (int*)alc(256 * 64 * 4);
  (void)ws_size; (void)in_sizes; (void)n_in; (void)out_size;

  hipMemsetAsync(HR, 0, 8388608ull * 2, stream);
  hipMemsetAsync(FLAG, 0, 256 * 64 * 4, stream);
  repack_w<<<dim3(131072), 256, 0, stream>>>(wih0, wihr, whh, WCAT);
  repack_x<<<dim3(8192), 256, 0, stream>>>(x, XP);
  bias_add<<<dim3(64), 256, 0, stream>>>(bih, bhh, BIAS);

  void* args[] = {&WCAT, &XP, &HR, &HOUT, &BIAS, &FLAG};
  hipLaunchCooperativeKernel((const void*)lstm_pipe, dim3(256), dim3(512),
                             args, 0, stream);

  lstm_head<<<dim3(512), 256, 0, stream>>>(HOUT, fcw, fcb, out);
}

// Round 5
// 15098.990 us; speedup vs baseline: 1.0180x; 1.0180x over previous
//
#include <hip/hip_runtime.h>

// LSTM: T=512, B=64, IN=512, H=1024, 4H=4096, LAYERS=4, OUT=1
// R9 = R5 (verified passing, 15.37 ms) with EXACTLY two latency-path edits,
// zero arithmetic changes:
//  (1) hot-spin polls (no s_sleep) — tests the DVFS/idle-downclock theory for
//      the structure-insensitive ~28 us/step period;
//  (2) ring backpressure amortized to every 8 steps (fNext >= t-24 covers
//      writes t..t+7; exactly sufficient: writes destroy h(t-32..t-25), and
//      fNext >= t-24 => consumer finished iter t-25 => those reads are done).
// Everything else byte-identical to R5: 256 WGs x 512 thr (8 waves), p2p
// flags FLAG[W] = completed steps posted after vmcnt-draining syncthreads,
// per-wave thresholds (P0: fPrev >= t+1; P1: fOwn >= t), W register-stationary,
// 32x32x16 MFMA, LDS atomicAdd reduction, double-buffered R.
// R6/R7/R8 (restructured waves + fences) failed verification with
// bit-identical errors across different binaries — abandoned as unexplained;
// this round re-establishes the verified base + one clean experiment.

typedef unsigned short u16;
typedef short bf16x8 __attribute__((ext_vector_type(8)));
typedef float f32x4 __attribute__((ext_vector_type(4)));
typedef float f32x16 __attribute__((ext_vector_type(16)));

__device__ __forceinline__ u16 f2bf(float f) {
  unsigned u = __float_as_uint(f);
  return (u16)((u + 0x7FFFu + ((u >> 16) & 1u)) >> 16);   // RNE
}
__device__ __forceinline__ float bf2f(u16 s) {
  return __uint_as_float(((unsigned)s) << 16);
}
__device__ __forceinline__ bf16x8 ld8(const u16* p) {
  uint4 v = *(const uint4*)p;
  return __builtin_bit_cast(bf16x8, v);
}
__device__ __forceinline__ float sigf(float x) {
  x = fminf(fmaxf(x, -30.f), 30.f);
  return 1.f / (1.f + __expf(-x));
}
__device__ __forceinline__ float tanhf_(float x) {
  x = fminf(fmaxf(x, -15.f), 15.f);
  float e = __expf(-2.f * x);
  return (1.f - e) / (1.f + e);
}

#define AT_LD(p) __hip_atomic_load((p), __ATOMIC_RELAXED, __HIP_MEMORY_SCOPE_AGENT)
#define AT_ST(p, v) __hip_atomic_store((p), (v), __ATOMIC_RELAXED, __HIP_MEMORY_SCOPE_AGENT)

// ---------------- repack: W -> WCAT[l][4096][2048] bf16 ----------------
// cols [0,Kx) = W_ih_l, [Kx,Kx+1024) = W_hh_l, rest 0. Kx = 512 (l=0) else 1024.
__global__ void repack_w(const float* __restrict__ wih0, const float* __restrict__ wihr,
                         const float* __restrict__ whh, u16* __restrict__ WCAT) {
  size_t i = (size_t)blockIdx.x * 256 + threadIdx.x;   // 33554432 total
  int l = (int)(i >> 23);
  int r = (int)(i >> 11) & 4095;
  int c = (int)i & 2047;
  int Kx = l ? 1024 : 512;
  float v = 0.f;
  if (c < Kx) v = l ? wihr[((size_t)(l - 1) * 4096 + r) * 1024 + c]
                    : wih0[(size_t)r * 512 + c];
  else if (c < Kx + 1024) v = whh[((size_t)l * 4096 + r) * 1024 + (c - Kx)];
  WCAT[i] = f2bf(v);
}

// ---------------- repack: x -> XP[t][kc(64)][b(64)][8] bf16 ----------------
__global__ void repack_x(const float* __restrict__ x, u16* __restrict__ XP) {
  int i = blockIdx.x * 256 + threadIdx.x;   // 2097152 total
  int t = i >> 12, r = i & 4095, kc = r >> 6, b = r & 63;
  const float* src = x + ((size_t)t * 64 + b) * 512 + kc * 8;
  float4 v0 = *(const float4*)src, v1 = *(const float4*)(src + 4);
  u16 o[8] = {f2bf(v0.x), f2bf(v0.y), f2bf(v0.z), f2bf(v0.w),
              f2bf(v1.x), f2bf(v1.y), f2bf(v1.z), f2bf(v1.w)};
  *(uint4*)(XP + ((size_t)(t * 64 + kc) * 64 + b) * 8) = *(uint4*)o;
}

__global__ void bias_add(const float* __restrict__ a, const float* __restrict__ b,
                         float* __restrict__ o) {
  int i = blockIdx.x * blockDim.x + threadIdx.x;   // 16384 total
  o[i] = a[i] + b[i];
}

// ---------------- pipelined recurrence ----------------
// WG w: layer = w>>6, owns units [16(w&63), +16) -> 64 gate-rows.
// 8 waves = (ks in 0..3, nh in 0..1): K-slice of NF frags (16k each), rows 32nh..+32.
// Each wave: 2 m-tiles (batch 0..31, 32..63) -> acc0/acc1, shared wf[] B-frags.
template <int NF, int FX>
__device__ __forceinline__ void run_pipe(
    int layer, int w64, const u16* __restrict__ WCAT, const u16* __restrict__ XP,
    u16* __restrict__ HR, u16* __restrict__ HOUT, const float* __restrict__ BIAS,
    int* __restrict__ FLAG, float* R) {
  const int tid = threadIdx.x;
  const int lane = tid & 63, wv = tid >> 6;
  const int ks = wv & 3, nh = wv >> 2;
  const int l31 = lane & 31, lhi = lane >> 5;
  const int W = layer * 64 + w64;

  // ---- W preload: NF frags = 4*NF VGPRs, persistent ----
  bf16x8 wf[NF];
  {
    const int lr = nh * 32 + l31;
    const int grow = (lr >> 4) * 1024 + 16 * w64 + (lr & 15);
    const u16* wrow = WCAT + ((size_t)layer * 4096 + grow) * 2048;
#pragma unroll
    for (int kk = 0; kk < NF; ++kk) {
      int f = ks * NF + kk;
      wf[kk] = ld8(wrow + f * 16 + lhi * 8);
    }
  }

  const int u = tid & 15, bp = tid >> 4;       // gating: (batch bp & bp+32, unit u)
  const int col = 16 * w64 + u;
  float c0 = 0.f, c1 = 0.f;
  const float bi = BIAS[layer * 4096 + col];
  const float bf_ = BIAS[layer * 4096 + 1024 + col];
  const float bg = BIAS[layer * 4096 + 2048 + col];
  const float bo = BIAS[layer * 4096 + 3072 + col];

  const int lane_base = (lhi * 64 + l31) * 8;  // mt0; mt1 adds +256 elems
  u16* HRL = HR + (size_t)layer * 2097152;                       // own ring (32 slots)
  const u16* M0B = (NF == 32) ? HR + (size_t)(layer - 1) * 2097152 : XP;
  const int lrD = nh * 32 + l31;               // C/D col -> local gate-row

  // ---- p2p sync setup: which inputs does THIS wave actually read? ----
  // wave covers frags [ks*NF, ks*NF+NF): f < FX  -> P0 (layer below / XP)
  //                                      f >= FX -> P1 (own-layer h(t-1))
  const bool needA = (layer > 0) && (ks * NF < FX);    // cross-layer P0
  const bool needB = (ks * NF + NF > FX);              // own-layer P1
  const bool needC = (layer < 3);                      // ring backpressure
  const int lm1 = (layer > 0) ? layer - 1 : layer;
  const int lp1 = (layer < 3) ? layer + 1 : layer;
  int* fA = FLAG + (lm1 * 64 + lane) * 64;
  int* fB = FLAG + (layer * 64 + lane) * 64;
  int* fC = FLAG + (lp1 * 64 + lane) * 64;
  const int NEVER = -0x40000000;

  // zero R buffer 0 (buffer 1 is zeroed in step 0's gate phase)
  *(f32x4*)&R[tid * 8] = f32x4{0.f, 0.f, 0.f, 0.f};
  *(f32x4*)&R[tid * 8 + 4] = f32x4{0.f, 0.f, 0.f, 0.f};
  __syncthreads();

  for (int t = 0; t < 512; ++t) {
    // ---- ring backpressure, amortized: safe for writes t..t+7 ----
    // (writes at s destroy h(s-32); fC >= t-24 => consumer finished iter t-25
    //  => all its reads of h(<= t-25) are complete. Hot spin, no s_sleep.)
    if (needC && (t & 7) == 0) {
      const int thC = t - 24;
      for (;;) {
        bool ok = AT_LD(fC) >= thC;
        if (__ballot(ok) == ~0ull) break;
      }
    }
    // ---- per-wave dependency poll (1-hop, hot spin) ----
    {
      const int thA = needA ? t + 1 : NEVER;   // layer l-1 finished t
      const int thB = needB ? t : NEVER;       // own layer finished t-1
      for (;;) {
        bool ok = (AT_LD(fA) >= thA) & (AT_LD(fB) >= thB);
        if (__ballot(ok) == ~0ull) break;
      }
    }

    float* Rb = R + (t & 1) * 4096;
    const u16* P0 = M0B + ((NF == 32) ? (size_t)(t & 31) * 65536
                                      : (size_t)t * 32768) + lane_base;
    const u16* P1 = HRL + (size_t)((t - 1) & 31) * 65536 + lane_base - (size_t)FX * 1024;

    f32x16 acc0 = {}, acc1 = {};
    uint4 a0[8], a1[8];
#pragma unroll
    for (int p = 0; p < 8; ++p) {
      int f = ks * NF + p;
      const u16* ap = (f < FX ? P0 : P1) + (size_t)f * 1024;
      a0[p] = *(const uint4*)ap;
      a1[p] = *(const uint4*)(ap + 256);
    }
#pragma unroll
    for (int kk = 0; kk < NF; ++kk) {
      uint4 ca = a0[kk & 7], cb = a1[kk & 7];
      if (kk + 8 < NF) {
        int f = ks * NF + kk + 8;
        const u16* ap = (f < FX ? P0 : P1) + (size_t)f * 1024;
        a0[kk & 7] = *(const uint4*)ap;
        a1[kk & 7] = *(const uint4*)(ap + 256);
      }
      acc0 = __builtin_amdgcn_mfma_f32_32x32x16_bf16(
          __builtin_bit_cast(bf16x8, ca), wf[kk], acc0, 0, 0, 0);
      acc1 = __builtin_amdgcn_mfma_f32_32x32x16_bf16(
          __builtin_bit_cast(bf16x8, cb), wf[kk], acc1, 0, 0, 0);
    }
#pragma unroll
    for (int r = 0; r < 16; ++r) {
      int m = (r & 3) + 8 * (r >> 2) + 4 * lhi;    // 32x32 C/D row map (m101)
      atomicAdd(&Rb[m * 64 + lrD], acc0[r]);
      atomicAdd(&Rb[(32 + m) * 64 + lrD], acc1[r]);
    }
    __syncthreads();
    {
      float p0i = Rb[bp * 64 + u] + bi, p0f = Rb[bp * 64 + 16 + u] + bf_;
      float p0g = Rb[bp * 64 + 32 + u] + bg, p0o = Rb[bp * 64 + 48 + u] + bo;
      float p1i = Rb[(bp + 32) * 64 + u] + bi, p1f = Rb[(bp + 32) * 64 + 16 + u] + bf_;
      float p1g = Rb[(bp + 32) * 64 + 32 + u] + bg, p1o = Rb[(bp + 32) * 64 + 48 + u] + bo;
      c0 = sigf(p0f) * c0 + sigf(p0i) * tanhf_(p0g);
      float h0 = sigf(p0o) * tanhf_(c0);
      c1 = sigf(p1f) * c1 + sigf(p1i) * tanhf_(p1g);
      float h1 = sigf(p1o) * tanhf_(c1);
      u16 hb0 = f2bf(h0), hb1 = f2bf(h1);
      unsigned n0 = (unsigned)(u16)__shfl_down((int)(unsigned)hb0, 1, 64);
      unsigned n1 = (unsigned)(u16)__shfl_down((int)(unsigned)hb1, 1, 64);
      if ((u & 1) == 0) {
        unsigned pk0 = (unsigned)hb0 | (n0 << 16);
        unsigned pk1 = (unsigned)hb1 | (n1 << 16);
        u16* slot = HRL + (size_t)(t & 31) * 65536;
        size_t e0 = ((size_t)(col >> 3) * 64 + bp) * 8 + (col & 7);
        AT_ST((unsigned*)(slot + e0), pk0);
        AT_ST((unsigned*)(slot + e0 + 256), pk1);   // b+32
        if (layer == 3 && bp == 31)                 // batch 63 for the head
          *(unsigned*)(HOUT + (size_t)t * 1024 + col) = pk1;
      }
      // fold zero-pass of the other R buffer into the gate phase
      float* Rn = R + ((t + 1) & 1) * 4096;
      *(f32x4*)&Rn[tid * 8] = f32x4{0.f, 0.f, 0.f, 0.f};
      *(f32x4*)&Rn[tid * 8 + 4] = f32x4{0.f, 0.f, 0.f, 0.f};
    }
    __syncthreads();   // drains vmcnt(0): ring stores at coherence point
    if (tid == 0) AT_ST(&FLAG[W * 64], t + 1);   // 1-hop progress post
  }
}

__global__ __launch_bounds__(512, 2) void lstm_pipe(
    const u16* __restrict__ WCAT, const u16* __restrict__ XP,
    u16* __restrict__ HR, u16* __restrict__ HOUT,
    const float* __restrict__ BIAS, int* __restrict__ FLAG) {
  __shared__ float R[2 * 4096];
  const int w = blockIdx.x;
  const int layer = w >> 6, w64 = w & 63;
  if (layer == 0) run_pipe<24, 32>(0, w64, WCAT, XP, HR, HOUT, BIAS, FLAG, R);
  else            run_pipe<32, 64>(layer, w64, WCAT, XP, HR, HOUT, BIAS, FLAG, R);
}

// ---------------- head: out[t] = sigmoid(h3[t][63][:]) . fcw + fcb ----------------
__global__ void lstm_head(const u16* __restrict__ Hl, const float* __restrict__ fcw,
                          const float* __restrict__ fcb, float* __restrict__ out) {
  int t = blockIdx.x, tid = threadIdx.x;
  const u16* hrow = Hl + (size_t)t * 1024;
  float s = 0.f;
  for (int j = tid; j < 1024; j += 256)
    s += sigf(bf2f(hrow[j])) * fcw[j];
  for (int o = 32; o; o >>= 1) s += __shfl_down(s, o, 64);
  __shared__ float red[4];
  if ((tid & 63) == 0) red[tid >> 6] = s;
  __syncthreads();
  if (tid == 0) out[t] = red[0] + red[1] + red[2] + red[3] + fcb[0];
}

// ---------------- launch ----------------
extern "C" void kernel_launch(void* const* d_in, const int* in_sizes, int n_in,
                              void* d_out, int out_size, void* d_ws, size_t ws_size,
                              hipStream_t stream) {
  const float* x    = (const float*)d_in[0];
  const float* wih0 = (const float*)d_in[1];
  const float* wihr = (const float*)d_in[2];
  const float* whh  = (const float*)d_in[3];
  const float* bih  = (const float*)d_in[4];
  const float* bhh  = (const float*)d_in[5];
  const float* fcw  = (const float*)d_in[6];
  const float* fcb  = (const float*)d_in[7];
  float* out = (float*)d_out;

  char* ws = (char*)d_ws;
  size_t off = 0;
  auto alc = [&](size_t b) { void* p = ws + off; off = (off + b + 255) & ~(size_t)255; return p; };
  u16* WCAT  = (u16*)alc(33554432ull * 2);   // 64 MB
  u16* XP    = (u16*)alc(16777216ull * 2);   // 32 MB
  u16* HR    = (u16*)alc(8388608ull * 2);    // 16 MB (4 layers x 32 slots x 128 KB)
  u16* HOUT  = (u16*)alc(524288ull * 2);     // 1 MB
  float* BIAS = (float*)alc(16384 * 4);
  int* FLAG  = (int*)alc(256 * 64 * 4);
  (void)ws_size; (void)in_sizes; (void)n_in; (void)out_size;

  hipMemsetAsync(HR, 0, 8388608ull * 2, stream);
  hipMemsetAsync(FLAG, 0, 256 * 64 * 4, stream);
  repack_w<<<dim3(131072), 256, 0, stream>>>(wih0, wihr, whh, WCAT);
  repack_x<<<dim3(8192), 256, 0, stream>>>(x, XP);
  bias_add<<<dim3(64), 256, 0, stream>>>(bih, bhh, BIAS);

  void* args[] = {&WCAT, &XP, &HR, &HOUT, &BIAS, &FLAG};
  hipLaunchCooperativeKernel((const void*)lstm_pipe, dim3(256), dim3(512),
                             args, 0, stream);

  lstm_head<<<dim3(512), 256, 0, stream>>>(HOUT, fcw, fcb, out);
}